// Round 5
// baseline (254.182 us; speedup 1.0000x reference)
//
#include <hip/hip_runtime.h>
#include <math.h>

typedef __bf16 bf16x8 __attribute__((ext_vector_type(8)));
typedef float  f32x4  __attribute__((ext_vector_type(4)));
typedef float  f32x16 __attribute__((ext_vector_type(16)));

#define MFMA16(a, b, c) __builtin_amdgcn_mfma_f32_16x16x32_bf16((a), (b), (c), 0, 0, 0)
#define MFMA32(a, b, c) __builtin_amdgcn_mfma_f32_32x32x16_bf16((a), (b), (c), 0, 0, 0)

__device__ __forceinline__ unsigned short f2bf(float f) {
    unsigned int u = __float_as_uint(f);
    u += 0x7fffu + ((u >> 16) & 1u);
    return (unsigned short)(u >> 16);
}

// async global->LDS DMA, 16 B per lane. LDS dest must be wave-uniform base +
// lane*16 (all call sites use lds + tid*8 ushorts).
__device__ __forceinline__ void gll16(const unsigned short* g, unsigned short* l) {
    __builtin_amdgcn_global_load_lds(
        (const __attribute__((address_space(1))) unsigned int*)g,
        (__attribute__((address_space(3))) unsigned int*)l, 16, 0, 0);
}

// ---------------------------------------------------------------------------
// Stage 0: fp32 -> bf16 conversion of h and the 4 weight matrices.
// wq is pre-scaled by 0.125*log2(e) so QK^T emerges in exp2 domain (drops a
// v_mul per score element in the attention softmax).
// ---------------------------------------------------------------------------
__global__ __launch_bounds__(256) void convert_kernel(
    const float* __restrict__ h, const float* __restrict__ wq,
    const float* __restrict__ wk, const float* __restrict__ wv,
    const float* __restrict__ wo,
    unsigned short* __restrict__ hb, unsigned short* __restrict__ wb)
{
    const int NH4 = 1572864;
    const int NW4 = 147456;
    int i4 = blockIdx.x * 256 + threadIdx.x;
    const float4* src;
    unsigned short* dst;
    int off;
    float sc = 1.0f;
    if (i4 < NH4) {
        src = (const float4*)h; dst = hb; off = i4;
    } else {
        int j = i4 - NH4;
        int w = j / NW4;
        off = j - w * NW4;
        const float* s = (w == 0) ? wq : (w == 1) ? wk : (w == 2) ? wv : wo;
        if (w == 0) sc = 0.18033688011112042f;   // 0.125 * log2(e)
        src = (const float4*)s;
        dst = wb + w * 589824;
    }
    float4 v = src[off];
    ushort4 o;
    o.x = f2bf(v.x * sc); o.y = f2bf(v.y * sc);
    o.z = f2bf(v.z * sc); o.w = f2bf(v.w * sc);
    ((ushort4*)dst)[off] = o;
}

// ---------------------------------------------------------------------------
// Stage 1/4: C = A @ B^T, double-buffered LDS + single barrier per K-iter.
// (R5 form, unchanged)
// ---------------------------------------------------------------------------
template <typename OutT>
__global__ __launch_bounds__(256) void gemm_bt(
    const unsigned short* __restrict__ A,
    const unsigned short* __restrict__ Bm,
    OutT* __restrict__ C)
{
    constexpr int K = 768, N = 768;
    __shared__ unsigned short As[2][128 * 32];
    __shared__ unsigned short Bs[2][128 * 32];
    const unsigned short* Bz = Bm + (size_t)blockIdx.z * N * K;
    OutT* Cz = C + (size_t)blockIdx.z * 8192 * N;

    const int tid  = threadIdx.x;
    const int bm   = blockIdx.x * 128, bn = blockIdx.y * 128;
    const int wave = tid >> 6, lane = tid & 63;
    const int wm   = (wave & 1) * 64, wn = (wave >> 1) * 64;
    const int l16  = lane & 15, quad = lane >> 4;

    const int sr  = tid >> 2;
    const int sp8 = ((tid & 3) ^ (sr & 3)) * 8;
    const int slot8 = (quad ^ (l16 & 3)) * 8;

    auto stage = [&](int k0, int bi) {
        gll16(A  + (size_t)(bm + sr) * K      + k0 + sp8, As[bi] + tid * 8);
        gll16(A  + (size_t)(bm + 64 + sr) * K + k0 + sp8, As[bi] + 2048 + tid * 8);
        gll16(Bz + (size_t)(bn + sr) * K      + k0 + sp8, Bs[bi] + tid * 8);
        gll16(Bz + (size_t)(bn + 64 + sr) * K + k0 + sp8, Bs[bi] + 2048 + tid * 8);
    };

    f32x4 acc[4][4] = {};

    stage(0, 0);
    __syncthreads();

    for (int i = 0; i < 24; i++) {
        const int cur = i & 1;
        if (i < 23) stage((i + 1) * 32, cur ^ 1);

        bf16x8 af[4], bfv[4];
        #pragma unroll
        for (int ii = 0; ii < 4; ii++)
            af[ii] = *(const bf16x8*)(As[cur] + (wm + ii * 16 + l16) * 32 + slot8);
        #pragma unroll
        for (int jj = 0; jj < 4; jj++)
            bfv[jj] = *(const bf16x8*)(Bs[cur] + (wn + jj * 16 + l16) * 32 + slot8);
        #pragma unroll
        for (int ii = 0; ii < 4; ii++)
            #pragma unroll
            for (int jj = 0; jj < 4; jj++)
                acc[ii][jj] = MFMA16(af[ii], bfv[jj], acc[ii][jj]);

        __syncthreads();
    }

    #pragma unroll
    for (int ii = 0; ii < 4; ii++) {
        #pragma unroll
        for (int jj = 0; jj < 4; jj++) {
            int row0 = bm + wm + ii * 16 + quad * 4;
            int col  = bn + wn + jj * 16 + l16;
            #pragma unroll
            for (int r = 0; r < 4; r++) {
                float v = acc[ii][jj][r];
                size_t idx = (size_t)(row0 + r) * N + col;
                if constexpr (sizeof(OutT) == 2) Cz[idx] = f2bf(v);
                else                             Cz[idx] = v;
            }
        }
    }
}

// ---------------------------------------------------------------------------
// Stage 2: transpose V per head: [B][24576][64] -> vt[B*12][64][2048].
// ---------------------------------------------------------------------------
__global__ __launch_bounds__(256) void vtrans_kernel(
    const unsigned short* __restrict__ Vg,
    unsigned short* __restrict__ vt)
{
    constexpr int LDT = 72;
    __shared__ unsigned short Ts[64 * LDT];
    const int b = blockIdx.z, hh = blockIdx.y, kp0 = blockIdx.x * 64;
    const int tid = threadIdx.x;
    const size_t boff = (size_t)b * (24576 * 64);
    const int rowV0 = hh * 2048 + kp0;

    #pragma unroll
    for (int rep = 0; rep < 2; rep++) {
        int idx = rep * 256 + tid;
        int r = idx >> 3, dp = (idx & 7) * 8;
        uint4 v = *(const uint4*)(Vg + boff + (size_t)(rowV0 + r) * 64 + dp);
        unsigned short tmp[8];
        *(uint4*)tmp = v;
        #pragma unroll
        for (int i = 0; i < 8; i++) Ts[(dp + i) * LDT + r] = tmp[i];
    }
    __syncthreads();
    unsigned short* vtb = vt + ((size_t)(b * 12 + hh)) * 64 * 2048;
    #pragma unroll
    for (int rep = 0; rep < 2; rep++) {
        int idx = rep * 256 + tid;
        int d = idx >> 3, kp = (idx & 7) * 8;
        uint4 v = *(const uint4*)(Ts + d * LDT + kp);
        *(uint4*)(vtb + (size_t)d * 2048 + kp0 + kp) = v;
    }
}

// ---------------------------------------------------------------------------
// Stage 3: flash attention. R14: split-K across blocks (SPLIT=2) — R3 showed
// the grid (768 blocks = 12 waves/CU ceiling) is the occupancy limiter, not
// VGPR/LDS. The softmax has no running max (direct exp2), so k-partials
// combine linearly: O = (O0+O1)/(l0+l1). Each kz-block processes 32 of the
// 64 k-tiles and writes raw f32 partial O + per-row partial l; a combine
// kernel normalizes. Grid 1536 -> 4 blocks/CU resident (VGPR cap) = 16
// waves/CU. Inner loop identical to the R13-proven counted-vmcnt ring
// (fused s_waitcnt+s_barrier asm, 3-buffer ring, prefetch distance 2).
// Also R14: finer chunk swizzle on K (^row>>3) and V (^row>>2) on BOTH the
// stage (global source) and read sides — spreads the 8-lane same-slot
// groups that doubled SQ_LDS_BANK_CONFLICT in R13.
// ---------------------------------------------------------------------------
template <int SPLIT>
__global__ __launch_bounds__(256) void attn_kernel(
    const unsigned short* __restrict__ Qg,
    const unsigned short* __restrict__ Kg,
    const unsigned short* __restrict__ vt,   // [B*12][64][2048]
    const int* __restrict__ mask,            // [B][2048]
    unsigned short* __restrict__ Og,         // [B][24576][64]  (SPLIT==1)
    float* __restrict__ Op,                  // [kz][B*24576*64] (SPLIT==2)
    float* __restrict__ lp)                  // [kz][B*24576]    (SPLIT==2)
{
    __shared__ unsigned short Ks[3 * 2048];  // 3 x [32 kpos][64 d] ring
    __shared__ unsigned short Vs[3 * 2048];  // 3 x [64 d][32 kpos] ring
    __shared__ unsigned long long msh[32];   // mask bitmap; read as u32[64]

    constexpr int NT = 64 / SPLIT;           // k-tiles per block
    const int z = blockIdx.z;
    const int b = z / SPLIT, kz = z % SPLIT;
    const int ktbase = kz * NT;
    const int hh = blockIdx.y, qt = blockIdx.x;
    const int tid  = threadIdx.x;
    const int wave = tid >> 6, lane = tid & 63;
    const int c31  = lane & 31, h = lane >> 5;
    const size_t boff = (size_t)b * (24576 * 64);
    const int rowQ0 = hh * 2048 + qt * 128;
    const int rowK0 = hh * 2048;
    const unsigned short* vtg = vt + ((size_t)(b * 12 + hh)) * 64 * 2048;
    // read-side swizzles (must equal the stage-side f(row) involutions)
    const int swk = (c31 & 7) ^ (c31 >> 3);          // K: f(r)=(r&7)^((r>>3)&3)
    const int swv = (c31 & 3) ^ ((c31 >> 2) & 3);    // V: f(r)=(r&3)^((r>>2)&3)

    // K staging: 32 rows x 64 d; row = tid>>3, chunk(8 of 16B) ^= f(row)
    const int srowK = tid >> 3;
    const int schK  = ((tid & 7) ^ (srowK & 7) ^ ((srowK >> 3) & 3)) * 8;
    // V staging: 64 rows x 32 k; row = tid>>2, chunk(4 of 16B) ^= f(row)
    const int srowV = tid >> 2;
    const int schV  = ((tid & 3) ^ (srowV & 3) ^ ((srowV >> 2) & 3)) * 8;

    auto stageKV = [&](int kt, int bi) {
        gll16(Kg  + boff + (size_t)(rowK0 + kt * 32 + srowK) * 64 + schK,
              Ks + bi * 2048 + tid * 8);
        gll16(vtg + (size_t)srowV * 2048 + kt * 32 + schV,
              Vs + bi * 2048 + tid * 8);
    };

    // Q tile: direct global -> registers. qf[c] holds k-slice c*16+8h+j for
    // q-row wave*32+c31, i.e. 16B chunk (2c+h) of the row.
    bf16x8 qf[4];
    {
        const unsigned short* qrow =
            Qg + boff + (size_t)(rowQ0 + wave * 32 + c31) * 64;
        #pragma unroll
        for (int c = 0; c < 4; c++)
            qf[c] = *(const bf16x8*)(qrow + (2 * c + h) * 8);
    }

    // build mask bitmap: thread t covers k-positions [t*8, t*8+8)
    {
        const int4 a = *(const int4*)(mask + b * 2048 + tid * 8);
        const int4 c = *(const int4*)(mask + b * 2048 + tid * 8 + 4);
        unsigned char byte =
            (a.x != 0 ? 1u : 0u)       | (a.y != 0 ? 2u : 0u) |
            (a.z != 0 ? 4u : 0u)       | (a.w != 0 ? 8u : 0u) |
            (c.x != 0 ? 16u : 0u)      | (c.y != 0 ? 32u : 0u) |
            (c.z != 0 ? 64u : 0u)      | (c.w != 0 ? 128u : 0u);
        ((unsigned char*)msh)[tid] = byte;
    }
    // publish msh; vmcnt == 0 entering the loop
    __syncthreads();

    // prologue prefetch: first two tiles of this block's k-range
    stageKV(ktbase + 0, 0);
    stageKV(ktbase + 1, 1);

    f32x16 acc[2] = {};                      // O: row=q-row fn(reg,h), col=d=nt*32+c31
    f32x16 acc_l  = {};                      // row-sum of P (ones-column MFMA)
    bf16x8 onesf;
    #pragma unroll
    for (int i = 0; i < 8; i++) onesf[i] = (__bf16)1.0f;

    int cur = 0;                             // ring index = lt % 3
    for (int lt = 0; lt < NT; lt++) {
        const int kt = ktbase + lt;
        // Fused wait+barrier, two-sided compiler memory fence (R12 lesson).
        // Tile lt's 2 DMAs retired (per-wave); up to 4 newer in flight.
        if (lt < NT - 1) asm volatile("s_waitcnt vmcnt(2)\n\ts_barrier" ::: "memory");
        else             asm volatile("s_waitcnt vmcnt(0)\n\ts_barrier" ::: "memory");
        __builtin_amdgcn_sched_barrier(0);

        if (lt < NT - 2) {
            int nb = cur + 2; if (nb >= 3) nb -= 3;
            stageKV(kt + 2, nb);             // overwrites buffer read at lt-1
        }

        const unsigned int am = ((const unsigned int*)msh)[kt];
        const unsigned short* Kc = Ks + cur * 2048;
        const unsigned short* Vc = Vs + cur * 2048;

        // S^T[kpos][qrow]: A = K rows (m=kpos 0..31), B = Q rows (n=qrow)
        f32x16 sT;
        {
            f32x16 z2 = {};
            __builtin_amdgcn_s_setprio(1);
            #pragma unroll
            for (int c = 0; c < 4; c++) {
                int ch = (2 * c + h) ^ swk;
                bf16x8 kf = *(const bf16x8*)(Kc + c31 * 64 + ch * 8);
                z2 = MFMA32(kf, qf[c], z2);
            }
            __builtin_amdgcn_s_setprio(0);
            sT = z2;
        }

        // softmax: P = rne_bf16(exp2(sT)) packed in-register; l via ones-MFMA.
        unsigned int p01[4], p23[4];
        if (am == 0xFFFFFFFFu) {
            #pragma unroll
            for (int s = 0; s < 4; s++) {
                float e0 = __builtin_amdgcn_exp2f(sT[4*s+0]);
                float e1 = __builtin_amdgcn_exp2f(sT[4*s+1]);
                float e2 = __builtin_amdgcn_exp2f(sT[4*s+2]);
                float e3 = __builtin_amdgcn_exp2f(sT[4*s+3]);
                asm("v_cvt_pk_bf16_f32 %0, %1, %2"
                    : "=v"(p01[s]) : "v"(e0), "v"(e1));
                asm("v_cvt_pk_bf16_f32 %0, %1, %2"
                    : "=v"(p23[s]) : "v"(e2), "v"(e3));
            }
        } else {
            #pragma unroll
            for (int s = 0; s < 4; s++) {
                unsigned int nib = (am >> (8 * s + 4 * h)) & 0xFu;
                float e0 = __builtin_amdgcn_exp2f(sT[4*s+0]);
                float e1 = __builtin_amdgcn_exp2f(sT[4*s+1]);
                float e2 = __builtin_amdgcn_exp2f(sT[4*s+2]);
                float e3 = __builtin_amdgcn_exp2f(sT[4*s+3]);
                e0 = (nib & 1u) ? e0 : 0.f;
                e1 = (nib & 2u) ? e1 : 0.f;
                e2 = (nib & 4u) ? e2 : 0.f;
                e3 = (nib & 8u) ? e3 : 0.f;
                asm("v_cvt_pk_bf16_f32 %0, %1, %2"
                    : "=v"(p01[s]) : "v"(e0), "v"(e1));
                asm("v_cvt_pk_bf16_f32 %0, %1, %2"
                    : "=v"(p23[s]) : "v"(e2), "v"(e3));
            }
        }

        // PV: A-frag (m=qrow=c31, k=kc*16+8h+j) from packed P in-register.
        __builtin_amdgcn_s_setprio(1);
        #pragma unroll
        for (int kc = 0; kc < 2; kc++) {
            unsigned int a01 = p01[2 * kc], b01 = p01[2 * kc + 1];
            unsigned int a23 = p23[2 * kc], b23 = p23[2 * kc + 1];
            asm("v_permlane32_swap_b32 %0, %1" : "+v"(a01), "+v"(b01));
            asm("v_permlane32_swap_b32 %0, %1" : "+v"(a23), "+v"(b23));
            uint4 pfu;
            pfu.x = a01;
            pfu.y = a23;
            pfu.z = b01;
            pfu.w = b23;
            bf16x8 pf;
            __builtin_memcpy(&pf, &pfu, 16);
            #pragma unroll
            for (int nt = 0; nt < 2; nt++) {
                int chv = (2 * kc + h) ^ swv;
                bf16x8 vf = *(const bf16x8*)(Vc + (nt * 32 + c31) * 32 + chv * 8);
                acc[nt] = MFMA32(pf, vf, acc[nt]);
            }
            acc_l = MFMA32(pf, onesf, acc_l);   // l[row] += sum_k P[row][k]
        }
        __builtin_amdgcn_s_setprio(0);

        cur = (cur == 2) ? 0 : cur + 1;
    }

    // epilogue: acc_l[reg] is the full row-sum (same reg->row map as acc).
    if constexpr (SPLIT == 1) {
        #pragma unroll
        for (int reg = 0; reg < 16; reg++) {
            int rowfn = (reg & 3) + 8 * (reg >> 2) + 4 * h;
            float li = __builtin_amdgcn_rcpf(acc_l[reg]);
            int row = rowQ0 + wave * 32 + rowfn;
            #pragma unroll
            for (int nt = 0; nt < 2; nt++)
                Og[boff + (size_t)row * 64 + nt * 32 + c31] = f2bf(acc[nt][reg] * li);
        }
    } else {
        float* Opz = Op + (size_t)kz * 6291456 + boff;
        float* lpz = lp + (size_t)kz * 98304 + b * 24576;
        #pragma unroll
        for (int reg = 0; reg < 16; reg++) {
            int rowfn = (reg & 3) + 8 * (reg >> 2) + 4 * h;
            int row = rowQ0 + wave * 32 + rowfn;
            #pragma unroll
            for (int nt = 0; nt < 2; nt++)
                Opz[(size_t)row * 64 + nt * 32 + c31] = acc[nt][reg];
            if (c31 == 0) lpz[row] = acc_l[reg];
        }
    }
}

// ---------------------------------------------------------------------------
// Stage 3b: combine the two k-split partials: ctx = (O0+O1)/(l0+l1), bf16.
// ---------------------------------------------------------------------------
__global__ __launch_bounds__(256) void combine_kernel(
    const float* __restrict__ Op,   // [2][6291456]
    const float* __restrict__ lp,   // [2][98304]
    unsigned short* __restrict__ ctx)
{
    const size_t idx8 = ((size_t)blockIdx.x * 256 + threadIdx.x) * 8;
    const int row = (int)(idx8 >> 6);
    const float linv = __builtin_amdgcn_rcpf(lp[row] + lp[98304 + row]);
    const float4 a0 = *(const float4*)(Op + idx8);
    const float4 a1 = *(const float4*)(Op + idx8 + 4);
    const float4 b0 = *(const float4*)(Op + 6291456 + idx8);
    const float4 b1 = *(const float4*)(Op + 6291456 + idx8 + 4);
    ushort4 o0, o1;
    o0.x = f2bf((a0.x + b0.x) * linv); o0.y = f2bf((a0.y + b0.y) * linv);
    o0.z = f2bf((a0.z + b0.z) * linv); o0.w = f2bf((a0.w + b0.w) * linv);
    o1.x = f2bf((a1.x + b1.x) * linv); o1.y = f2bf((a1.y + b1.y) * linv);
    o1.z = f2bf((a1.z + b1.z) * linv); o1.w = f2bf((a1.w + b1.w) * linv);
    *(ushort4*)(ctx + idx8)     = o0;
    *(ushort4*)(ctx + idx8 + 4) = o1;
}

// ---------------------------------------------------------------------------
extern "C" void kernel_launch(void* const* d_in, const int* in_sizes, int n_in,
                              void* d_out, int out_size, void* d_ws, size_t ws_size,
                              hipStream_t stream)
{
    const float* h    = (const float*)d_in[0];
    const int*   mask = (const int*)d_in[1];
    const float* wq   = (const float*)d_in[2];
    const float* wk   = (const float*)d_in[3];
    const float* wv   = (const float*)d_in[4];
    const float* wo   = (const float*)d_in[5];

    // ws layout (ushorts): hb (reused as V^T) | wb | qkv | ctx = 67.6 MB,
    // then (split-K path only) f32 partials Op (50.3 MB) + lp (0.8 MB).
    unsigned short* hb  = (unsigned short*)d_ws;
    unsigned short* wb  = hb + 6291456;
    unsigned short* qkv = wb + 4 * 589824;
    unsigned short* ctx = qkv + (size_t)3 * 6291456;
    float* Op = (float*)(ctx + 6291456);
    float* lp = Op + (size_t)2 * 6291456;
    const size_t ws_need = 33816576ull * 2            // bf16 region
                         + (2ull * 6291456 + 2ull * 98304) * 4;
    const bool split = ws_size >= ws_need;

    convert_kernel<<<8448, 256, 0, stream>>>(h, wq, wk, wv, wo, hb, wb);
    gemm_bt<unsigned short><<<dim3(64, 6, 3), 256, 0, stream>>>(hb, wb, qkv);
    // hb is dead now -> reuse as V^T
    vtrans_kernel<<<dim3(32, 12, 4), 256, 0, stream>>>(qkv + (size_t)2 * 6291456, hb);
    if (split) {
        attn_kernel<2><<<dim3(16, 12, 8), 256, 0, stream>>>(
            qkv, qkv + 6291456, hb, mask, ctx, Op, lp);
        combine_kernel<<<3072, 256, 0, stream>>>(Op, lp, ctx);
    } else {
        attn_kernel<1><<<dim3(16, 12, 4), 256, 0, stream>>>(
            qkv, qkv + 6291456, hb, mask, ctx, nullptr, nullptr);
    }
    gemm_bt<float><<<dim3(64, 6, 1), 256, 0, stream>>>(
        ctx, wb + (size_t)3 * 589824, (float*)d_out);
}

// Round 6
// 239.847 us; speedup vs baseline: 1.0598x; 1.0598x over previous
//
#include <hip/hip_runtime.h>
#include <math.h>

typedef __bf16 bf16x8 __attribute__((ext_vector_type(8)));
typedef float  f32x4  __attribute__((ext_vector_type(4)));
typedef float  f32x16 __attribute__((ext_vector_type(16)));

#define MFMA16(a, b, c) __builtin_amdgcn_mfma_f32_16x16x32_bf16((a), (b), (c), 0, 0, 0)
#define MFMA32(a, b, c) __builtin_amdgcn_mfma_f32_32x32x16_bf16((a), (b), (c), 0, 0, 0)

__device__ __forceinline__ unsigned short f2bf(float f) {
    unsigned int u = __float_as_uint(f);
    u += 0x7fffu + ((u >> 16) & 1u);
    return (unsigned short)(u >> 16);
}

// async global->LDS DMA, 16 B per lane. LDS dest must be wave-uniform base +
// lane*16 (all call sites use lds + tid*8 ushorts).
__device__ __forceinline__ void gll16(const unsigned short* g, unsigned short* l) {
    __builtin_amdgcn_global_load_lds(
        (const __attribute__((address_space(1))) unsigned int*)g,
        (__attribute__((address_space(3))) unsigned int*)l, 16, 0, 0);
}

// ---------------------------------------------------------------------------
// Stage 0: fp32 -> bf16 conversion of h and the 4 weight matrices.
// wq is pre-scaled by 0.125*log2(e) so QK^T emerges in exp2 domain (drops a
// v_mul per score element in the attention softmax).
// ---------------------------------------------------------------------------
__global__ __launch_bounds__(256) void convert_kernel(
    const float* __restrict__ h, const float* __restrict__ wq,
    const float* __restrict__ wk, const float* __restrict__ wv,
    const float* __restrict__ wo,
    unsigned short* __restrict__ hb, unsigned short* __restrict__ wb)
{
    const int NH4 = 1572864;
    const int NW4 = 147456;
    int i4 = blockIdx.x * 256 + threadIdx.x;
    const float4* src;
    unsigned short* dst;
    int off;
    float sc = 1.0f;
    if (i4 < NH4) {
        src = (const float4*)h; dst = hb; off = i4;
    } else {
        int j = i4 - NH4;
        int w = j / NW4;
        off = j - w * NW4;
        const float* s = (w == 0) ? wq : (w == 1) ? wk : (w == 2) ? wv : wo;
        if (w == 0) sc = 0.18033688011112042f;   // 0.125 * log2(e)
        src = (const float4*)s;
        dst = wb + w * 589824;
    }
    float4 v = src[off];
    ushort4 o;
    o.x = f2bf(v.x * sc); o.y = f2bf(v.y * sc);
    o.z = f2bf(v.z * sc); o.w = f2bf(v.w * sc);
    ((ushort4*)dst)[off] = o;
}

// ---------------------------------------------------------------------------
// Stage 1/4: C = A @ B^T. R15: counted-vmcnt 3-buffer ring (the R12/R13-
// proven fused s_waitcnt+s_barrier skeleton, ported from attn) replaces the
// old __syncthreads() per K-iter, whose compiler-lowered vmcnt(0) drained
// the prefetch DMA issued the same iteration (~500+ exposed cycles x 24
// iters at only ~3 blocks/CU of cover). Also R15: flat grid + XCD-chunked
// swizzle, decomposed bn-fastest: the 6 blocks sharing an A-panel become
// ADJACENT ids within one XCD's contiguous chunk -> A-panel read ~once per
// XCD from L2; the whole B slice (1.1 MB) is L2-resident.
// Ring invariants (as attn):
//   - tile i's 4 DMAs/wave issued at iter i-2 -> 2 iter-times to land.
//   - per iter: s_waitcnt vmcnt(4); s_barrier (ONE asm, "memory" clobber:
//     two-sided compiler fence) -> stage(i+2) -> ds_read + MFMA.
//   - WAR: buffer (i+2)%3 was last read at iter i-1; the barrier at iter i
//     separates those reads (already consumed into VGPRs) from new writes.
//   - RAW: every wave passed vmcnt(4) before the barrier => all 16 block
//     loads of tile i are in LDS when the barrier releases.
// ---------------------------------------------------------------------------
template <typename OutT>
__global__ __launch_bounds__(256) void gemm_bt(
    const unsigned short* __restrict__ A,
    const unsigned short* __restrict__ Bm,
    OutT* __restrict__ C)
{
    constexpr int K = 768, N = 768;
    __shared__ unsigned short As[3][128 * 32];
    __shared__ unsigned short Bs[3][128 * 32];

    // flat grid, XCD-chunked bijective swizzle (gridDim.x % 8 == 0).
    // lid decomposition: bn fastest (6 tiles) -> groups of 6 consecutive
    // lids share one A-panel; then bm (64), then z.
    const int nwg  = gridDim.x;
    const int orig = blockIdx.x;
    const int lid  = (orig & 7) * (nwg >> 3) + (orig >> 3);
    const int nx   = lid % 6;
    const int t    = lid / 6;
    const int bm   = (t & 63) * 128, bn = nx * 128;
    const int bz   = t >> 6;

    const unsigned short* Bz = Bm + (size_t)bz * N * K;
    OutT* Cz = C + (size_t)bz * 8192 * N;

    const int tid  = threadIdx.x;
    const int wave = tid >> 6, lane = tid & 63;
    const int wm   = (wave & 1) * 64, wn = (wave >> 1) * 64;
    const int l16  = lane & 15, quad = lane >> 4;

    const int sr  = tid >> 2;
    const int sp8 = ((tid & 3) ^ (sr & 3)) * 8;
    const int slot8 = (quad ^ (l16 & 3)) * 8;

    auto stage = [&](int k0, int bi) {
        gll16(A  + (size_t)(bm + sr) * K      + k0 + sp8, As[bi] + tid * 8);
        gll16(A  + (size_t)(bm + 64 + sr) * K + k0 + sp8, As[bi] + 2048 + tid * 8);
        gll16(Bz + (size_t)(bn + sr) * K      + k0 + sp8, Bs[bi] + tid * 8);
        gll16(Bz + (size_t)(bn + 64 + sr) * K + k0 + sp8, Bs[bi] + 2048 + tid * 8);
    };

    f32x4 acc[4][4] = {};

    // prologue prefetch: K-tiles 0 and 1 -> 8 outstanding DMAs per wave
    stage(0, 0);
    stage(32, 1);

    int cur = 0;                             // ring index = i % 3
    for (int i = 0; i < 24; i++) {
        // Fused wait+barrier (two-sided fence). Tile i's 4 DMAs retired
        // per-wave; up to 8 newer (i+1, i+2) stay in flight.
        if (i < 23) asm volatile("s_waitcnt vmcnt(4)\n\ts_barrier" ::: "memory");
        else        asm volatile("s_waitcnt vmcnt(0)\n\ts_barrier" ::: "memory");
        __builtin_amdgcn_sched_barrier(0);

        if (i < 22) {
            int nb = cur + 2; if (nb >= 3) nb -= 3;
            stage((i + 2) * 32, nb);         // overwrites buffer read at i-1
        }

        bf16x8 af[4], bfv[4];
        #pragma unroll
        for (int ii = 0; ii < 4; ii++)
            af[ii] = *(const bf16x8*)(As[cur] + (wm + ii * 16 + l16) * 32 + slot8);
        #pragma unroll
        for (int jj = 0; jj < 4; jj++)
            bfv[jj] = *(const bf16x8*)(Bs[cur] + (wn + jj * 16 + l16) * 32 + slot8);
        #pragma unroll
        for (int ii = 0; ii < 4; ii++)
            #pragma unroll
            for (int jj = 0; jj < 4; jj++)
                acc[ii][jj] = MFMA16(af[ii], bfv[jj], acc[ii][jj]);

        cur = (cur == 2) ? 0 : cur + 1;
    }

    #pragma unroll
    for (int ii = 0; ii < 4; ii++) {
        #pragma unroll
        for (int jj = 0; jj < 4; jj++) {
            int row0 = bm + wm + ii * 16 + quad * 4;
            int col  = bn + wn + jj * 16 + l16;
            #pragma unroll
            for (int r = 0; r < 4; r++) {
                float v = acc[ii][jj][r];
                size_t idx = (size_t)(row0 + r) * N + col;
                if constexpr (sizeof(OutT) == 2) Cz[idx] = f2bf(v);
                else                             Cz[idx] = v;
            }
        }
    }
}

// ---------------------------------------------------------------------------
// Stage 2: transpose V per head: [B][24576][64] -> vt[B*12][64][2048].
// ---------------------------------------------------------------------------
__global__ __launch_bounds__(256) void vtrans_kernel(
    const unsigned short* __restrict__ Vg,
    unsigned short* __restrict__ vt)
{
    constexpr int LDT = 72;
    __shared__ unsigned short Ts[64 * LDT];
    const int b = blockIdx.z, hh = blockIdx.y, kp0 = blockIdx.x * 64;
    const int tid = threadIdx.x;
    const size_t boff = (size_t)b * (24576 * 64);
    const int rowV0 = hh * 2048 + kp0;

    #pragma unroll
    for (int rep = 0; rep < 2; rep++) {
        int idx = rep * 256 + tid;
        int r = idx >> 3, dp = (idx & 7) * 8;
        uint4 v = *(const uint4*)(Vg + boff + (size_t)(rowV0 + r) * 64 + dp);
        unsigned short tmp[8];
        *(uint4*)tmp = v;
        #pragma unroll
        for (int i = 0; i < 8; i++) Ts[(dp + i) * LDT + r] = tmp[i];
    }
    __syncthreads();
    unsigned short* vtb = vt + ((size_t)(b * 12 + hh)) * 64 * 2048;
    #pragma unroll
    for (int rep = 0; rep < 2; rep++) {
        int idx = rep * 256 + tid;
        int d = idx >> 3, kp = (idx & 7) * 8;
        uint4 v = *(const uint4*)(Ts + d * LDT + kp);
        *(uint4*)(vtb + (size_t)d * 2048 + kp0 + kp) = v;
    }
}

// ---------------------------------------------------------------------------
// Stage 3: flash attention, single-pass (R3 structure — split-K reverted:
// R4 showed occupancy is NOT grid-limited; split-K only added 4x write
// traffic + a combine pass, net -10 us). Keeps:
//   - KVBLK=32 counted-vmcnt 3-buffer ring, fused s_waitcnt+s_barrier
//     (R12 race lesson), prefetch distance 2, never drains in the loop.
//   - R14 fine stage/read swizzles (K: ^(r&7)^((r>>3)&3), V: ^(r&3)^
//     ((r>>2)&3)) — measured SQ_LDS_BANK_CONFLICT 12.6M -> 0.
//   - T5 setprio around MFMA clusters, in-register P via cvt_pk+permlane,
//     l via ones-column MFMA (epilogue needs no cross-lane combine).
// ---------------------------------------------------------------------------
__global__ __launch_bounds__(256) void attn_kernel(
    const unsigned short* __restrict__ Qg,
    const unsigned short* __restrict__ Kg,
    const unsigned short* __restrict__ vt,   // [B*12][64][2048]
    const int* __restrict__ mask,            // [B][2048]
    unsigned short* __restrict__ Og)         // [B][24576][64]
{
    __shared__ unsigned short Ks[3 * 2048];  // 3 x [32 kpos][64 d] ring
    __shared__ unsigned short Vs[3 * 2048];  // 3 x [64 d][32 kpos] ring
    __shared__ unsigned long long msh[32];   // mask bitmap; read as u32[64]

    const int b = blockIdx.z, hh = blockIdx.y, qt = blockIdx.x;
    const int tid  = threadIdx.x;
    const int wave = tid >> 6, lane = tid & 63;
    const int c31  = lane & 31, h = lane >> 5;
    const size_t boff = (size_t)b * (24576 * 64);
    const int rowQ0 = hh * 2048 + qt * 128;
    const int rowK0 = hh * 2048;
    const unsigned short* vtg = vt + ((size_t)(b * 12 + hh)) * 64 * 2048;
    // read-side swizzles (must equal the stage-side f(row) involutions)
    const int swk = (c31 & 7) ^ (c31 >> 3);          // K: f(r)=(r&7)^((r>>3)&3)
    const int swv = (c31 & 3) ^ ((c31 >> 2) & 3);    // V: f(r)=(r&3)^((r>>2)&3)

    // K staging: 32 rows x 64 d; row = tid>>3, chunk(8 of 16B) ^= f(row)
    const int srowK = tid >> 3;
    const int schK  = ((tid & 7) ^ (srowK & 7) ^ ((srowK >> 3) & 3)) * 8;
    // V staging: 64 rows x 32 k; row = tid>>2, chunk(4 of 16B) ^= f(row)
    const int srowV = tid >> 2;
    const int schV  = ((tid & 3) ^ (srowV & 3) ^ ((srowV >> 2) & 3)) * 8;

    auto stageKV = [&](int kt, int bi) {
        gll16(Kg  + boff + (size_t)(rowK0 + kt * 32 + srowK) * 64 + schK,
              Ks + bi * 2048 + tid * 8);
        gll16(vtg + (size_t)srowV * 2048 + kt * 32 + schV,
              Vs + bi * 2048 + tid * 8);
    };

    // Q tile: direct global -> registers. qf[c] holds k-slice c*16+8h+j for
    // q-row wave*32+c31, i.e. 16B chunk (2c+h) of the row.
    bf16x8 qf[4];
    {
        const unsigned short* qrow =
            Qg + boff + (size_t)(rowQ0 + wave * 32 + c31) * 64;
        #pragma unroll
        for (int c = 0; c < 4; c++)
            qf[c] = *(const bf16x8*)(qrow + (2 * c + h) * 8);
    }

    // build mask bitmap: thread t covers k-positions [t*8, t*8+8)
    {
        const int4 a = *(const int4*)(mask + b * 2048 + tid * 8);
        const int4 c = *(const int4*)(mask + b * 2048 + tid * 8 + 4);
        unsigned char byte =
            (a.x != 0 ? 1u : 0u)       | (a.y != 0 ? 2u : 0u) |
            (a.z != 0 ? 4u : 0u)       | (a.w != 0 ? 8u : 0u) |
            (c.x != 0 ? 16u : 0u)      | (c.y != 0 ? 32u : 0u) |
            (c.z != 0 ? 64u : 0u)      | (c.w != 0 ? 128u : 0u);
        ((unsigned char*)msh)[tid] = byte;
    }
    // publish msh; vmcnt == 0 entering the loop
    __syncthreads();

    // prologue prefetch: tiles 0 and 1 -> 4 outstanding DMAs per wave
    stageKV(0, 0);
    stageKV(1, 1);

    f32x16 acc[2] = {};                      // O: row=q-row fn(reg,h), col=d=nt*32+c31
    f32x16 acc_l  = {};                      // row-sum of P (ones-column MFMA)
    bf16x8 onesf;
    #pragma unroll
    for (int i = 0; i < 8; i++) onesf[i] = (__bf16)1.0f;

    int cur = 0;                             // ring index = kt % 3
    for (int kt = 0; kt < 64; kt++) {
        // Fused wait+barrier, two-sided compiler memory fence (R12 lesson).
        // Tile kt's 2 DMAs retired (per-wave); up to 4 newer in flight.
        if (kt < 63) asm volatile("s_waitcnt vmcnt(2)\n\ts_barrier" ::: "memory");
        else         asm volatile("s_waitcnt vmcnt(0)\n\ts_barrier" ::: "memory");
        __builtin_amdgcn_sched_barrier(0);

        if (kt < 62) {
            int nb = cur + 2; if (nb >= 3) nb -= 3;
            stageKV(kt + 2, nb);             // overwrites buffer read at kt-1
        }

        const unsigned int am = ((const unsigned int*)msh)[kt];
        const unsigned short* Kc = Ks + cur * 2048;
        const unsigned short* Vc = Vs + cur * 2048;

        // S^T[kpos][qrow]: A = K rows (m=kpos 0..31), B = Q rows (n=qrow)
        f32x16 sT;
        {
            f32x16 z2 = {};
            __builtin_amdgcn_s_setprio(1);
            #pragma unroll
            for (int c = 0; c < 4; c++) {
                int ch = (2 * c + h) ^ swk;
                bf16x8 kf = *(const bf16x8*)(Kc + c31 * 64 + ch * 8);
                z2 = MFMA32(kf, qf[c], z2);
            }
            __builtin_amdgcn_s_setprio(0);
            sT = z2;
        }

        // softmax: P = rne_bf16(exp2(sT)) packed in-register; l via ones-MFMA.
        unsigned int p01[4], p23[4];
        if (am == 0xFFFFFFFFu) {
            #pragma unroll
            for (int s = 0; s < 4; s++) {
                float e0 = __builtin_amdgcn_exp2f(sT[4*s+0]);
                float e1 = __builtin_amdgcn_exp2f(sT[4*s+1]);
                float e2 = __builtin_amdgcn_exp2f(sT[4*s+2]);
                float e3 = __builtin_amdgcn_exp2f(sT[4*s+3]);
                asm("v_cvt_pk_bf16_f32 %0, %1, %2"
                    : "=v"(p01[s]) : "v"(e0), "v"(e1));
                asm("v_cvt_pk_bf16_f32 %0, %1, %2"
                    : "=v"(p23[s]) : "v"(e2), "v"(e3));
            }
        } else {
            #pragma unroll
            for (int s = 0; s < 4; s++) {
                unsigned int nib = (am >> (8 * s + 4 * h)) & 0xFu;
                float e0 = __builtin_amdgcn_exp2f(sT[4*s+0]);
                float e1 = __builtin_amdgcn_exp2f(sT[4*s+1]);
                float e2 = __builtin_amdgcn_exp2f(sT[4*s+2]);
                float e3 = __builtin_amdgcn_exp2f(sT[4*s+3]);
                e0 = (nib & 1u) ? e0 : 0.f;
                e1 = (nib & 2u) ? e1 : 0.f;
                e2 = (nib & 4u) ? e2 : 0.f;
                e3 = (nib & 8u) ? e3 : 0.f;
                asm("v_cvt_pk_bf16_f32 %0, %1, %2"
                    : "=v"(p01[s]) : "v"(e0), "v"(e1));
                asm("v_cvt_pk_bf16_f32 %0, %1, %2"
                    : "=v"(p23[s]) : "v"(e2), "v"(e3));
            }
        }

        // PV: A-frag (m=qrow=c31, k=kc*16+8h+j) from packed P in-register.
        __builtin_amdgcn_s_setprio(1);
        #pragma unroll
        for (int kc = 0; kc < 2; kc++) {
            unsigned int a01 = p01[2 * kc], b01 = p01[2 * kc + 1];
            unsigned int a23 = p23[2 * kc], b23 = p23[2 * kc + 1];
            asm("v_permlane32_swap_b32 %0, %1" : "+v"(a01), "+v"(b01));
            asm("v_permlane32_swap_b32 %0, %1" : "+v"(a23), "+v"(b23));
            uint4 pfu;
            pfu.x = a01;
            pfu.y = a23;
            pfu.z = b01;
            pfu.w = b23;
            bf16x8 pf;
            __builtin_memcpy(&pf, &pfu, 16);
            #pragma unroll
            for (int nt = 0; nt < 2; nt++) {
                int chv = (2 * kc + h) ^ swv;
                bf16x8 vf = *(const bf16x8*)(Vc + (nt * 32 + c31) * 32 + chv * 8);
                acc[nt] = MFMA32(pf, vf, acc[nt]);
            }
            acc_l = MFMA32(pf, onesf, acc_l);   // l[row] += sum_k P[row][k]
        }
        __builtin_amdgcn_s_setprio(0);

        cur = (cur == 2) ? 0 : cur + 1;
    }

    // epilogue: acc_l[reg] is the full row-sum (same reg->row map as acc) —
    // no cross-lane combine needed.
    #pragma unroll
    for (int reg = 0; reg < 16; reg++) {
        int rowfn = (reg & 3) + 8 * (reg >> 2) + 4 * h;
        float li = __builtin_amdgcn_rcpf(acc_l[reg]);
        int row = rowQ0 + wave * 32 + rowfn;
        #pragma unroll
        for (int nt = 0; nt < 2; nt++)
            Og[boff + (size_t)row * 64 + nt * 32 + c31] = f2bf(acc[nt][reg] * li);
    }
}

// ---------------------------------------------------------------------------
extern "C" void kernel_launch(void* const* d_in, const int* in_sizes, int n_in,
                              void* d_out, int out_size, void* d_ws, size_t ws_size,
                              hipStream_t stream)
{
    const float* h    = (const float*)d_in[0];
    const int*   mask = (const int*)d_in[1];
    const float* wq   = (const float*)d_in[2];
    const float* wk   = (const float*)d_in[3];
    const float* wv   = (const float*)d_in[4];
    const float* wo   = (const float*)d_in[5];

    // ws layout (ushorts): hb (reused as V^T) | wb | qkv | ctx = 67.6 MB
    unsigned short* hb  = (unsigned short*)d_ws;
    unsigned short* wb  = hb + 6291456;
    unsigned short* qkv = wb + 4 * 589824;
    unsigned short* ctx = qkv + (size_t)3 * 6291456;

    convert_kernel<<<8448, 256, 0, stream>>>(h, wq, wk, wv, wo, hb, wb);
    gemm_bt<unsigned short><<<1152, 256, 0, stream>>>(hb, wb, qkv);
    // hb is dead now -> reuse as V^T
    vtrans_kernel<<<dim3(32, 12, 4), 256, 0, stream>>>(qkv + (size_t)2 * 6291456, hb);
    attn_kernel<<<dim3(16, 12, 4), 256, 0, stream>>>(
        qkv, qkv + 6291456, hb, mask, ctx);
    gemm_bt<float><<<384, 256, 0, stream>>>(
        ctx, wb + (size_t)3 * 589824, (float*)d_out);
}